// Round 7
// baseline (342.982 us; speedup 1.0000x reference)
//
#include <hip/hip_runtime.h>
#include <float.h>

#define DECAY 0.99f
#define EPS 1e-5f
#define NROWS 65536
#define DIM 256
#define NEMB 1024
#define CH 64            // rows per sub-chunk in segmented reduction
#define MAXSUB 2048      // NROWS/CH + NEMB upper bound on total sub-chunks

#define GLOBAL_AS __attribute__((address_space(1)))
#define LOCAL_AS  __attribute__((address_space(3)))

typedef _Float16 f16;
typedef _Float16 half8 __attribute__((ext_vector_type(8)));
typedef float f32x4 __attribute__((ext_vector_type(4)));

// ---------- K0a: ||e_k||^2 per code + zero counts ----------
__global__ __launch_bounds__(256) void k_enorm(const float* __restrict__ embed,
                                               float* __restrict__ enorm2,
                                               int* __restrict__ counts) {
    int kk = threadIdx.x & 63;
    int dg = threadIdx.x >> 6;              // 0..3
    int k  = blockIdx.x * 64 + kk;          // 16 blocks * 64 = 1024 codes
    float s = 0.f;
    for (int d = dg; d < DIM; d += 4) {
        float v = embed[(size_t)d * NEMB + k];
        s = fmaf(v, v, s);
    }
    __shared__ float red[4][64];
    red[dg][kk] = s;
    __syncthreads();
    if (dg == 0) enorm2[k] = red[0][kk] + red[1][kk] + red[2][kk] + red[3][kk];
    int gt = blockIdx.x * 256 + threadIdx.x;
    if (gt < NEMB) counts[gt] = 0;
}

// ---------- K0b: fused transpose (embedT fp32) + hi/lo split (ehlT f16) ----------
__global__ __launch_bounds__(256) void k_prep(const float* __restrict__ embed,
                                              float* __restrict__ embedT,
                                              f16* __restrict__ ehlT) {
    __shared__ float tile[32][33];           // [d-local][c-local]
    int c0 = blockIdx.x * 32, d0 = blockIdx.y * 32;
    int tx = threadIdx.x, ty = threadIdx.y;  // 32 x 8
#pragma unroll
    for (int i = 0; i < 4; i++)
        tile[ty + 8 * i][tx] = embed[(size_t)(d0 + ty + 8 * i) * NEMB + c0 + tx];
    __syncthreads();
#pragma unroll
    for (int i = 0; i < 4; i++) {
        int c = c0 + ty + 8 * i;
        int d = d0 + tx;
        float v = tile[tx][ty + 8 * i];
        embedT[(size_t)c * DIM + d] = v;
        f16 h = (f16)v;
        ehlT[(size_t)c * 512 + d]       = h;
        ehlT[(size_t)c * 512 + 256 + d] = (f16)(v - (float)h);
    }
}

// ---------- K0d: input fp32 [65536][256] -> xhl f16 [65536][512] (hi||lo) ----------
__global__ __launch_bounds__(512) void k_xsplit(const float* __restrict__ input,
                                                f16* __restrict__ xhl) {
    int g = blockIdx.x * 512 + threadIdx.x;    // 0..2097151
    int row = g >> 5, dq = g & 31;             // dq = 8-float granule
    const float4* s = (const float4*)(input + (size_t)row * DIM + dq * 8);
    float4 v0 = s[0], v1 = s[1];
    float fv[8] = {v0.x, v0.y, v0.z, v0.w, v1.x, v1.y, v1.z, v1.w};
    half8 h, l;
#pragma unroll
    for (int e = 0; e < 8; ++e) {
        f16 hh = (f16)fv[e];
        h[e] = hh;
        l[e] = (f16)(fv[e] - (float)hh);
    }
    *(half8*)(xhl + (size_t)row * 512 + dq * 8)       = h;
    *(half8*)(xhl + (size_t)row * 512 + 256 + dq * 8) = l;
}

// ---------- K1: MFMA GEMM-argmin v5: counted-vmcnt pipeline ----------
// BM=256 rows/block (grid=256=1/CU), 4 col-slabs of 256, BK=64, effK=768 (12 K-tiles/slab).
// 8 waves (2Mx4N), wave tile 128x64: 24 ds_read_b128 / 64 MFMA per K-tile.
// A,B staged via global_load_lds: linear dest chunks of 1KB (8 rows x 128B);
// per-lane src row=8c+(l>>3), kslot=(l&7)^(l>>3) reproduces LDS layout
// byte(row,slot) = row*128 + ((slot*16) ^ ((row&7)<<4))  [proven low-conflict].
// Per K-tile g: [barrier(A); issue 8 loads (g+1) -> buf^1; s_waitcnt vmcnt(8)
// (FIFO => tile g's 8 landed); barrier(B); 4 phases reads+MFMA, no barriers].
#define LDS_A0 0
#define LDS_A1 32768
#define LDS_B0 65536
#define LDS_B1 98304
#define LDS_PV 131072    // float[256][4]
#define LDS_PI 135168    // int[256][4]
#define LDS_SZ 139264

__device__ __forceinline__ void stage_tile(const f16* __restrict__ xhl,
                                           const f16* __restrict__ ehlT,
                                           char* dA, char* dB,
                                           int rb, int gn, int w, int rA, int ksx) {
    int slab_n = gn / 12, kt_n = gn % 12;
    int ka = (kt_n < 4) ? kt_n * 64 : (kt_n < 8 ? 256 + (kt_n - 4) * 64 : (kt_n - 8) * 64);
    int kb = (kt_n < 4) ? kt_n * 64 : (kt_n < 8 ? (kt_n - 4) * 64 : 256 + (kt_n - 8) * 64);
    int cbn = slab_n * 256;
#pragma unroll
    for (int j = 0; j < 4; ++j) {
        const f16* s = xhl + (size_t)(rb + j * 64 + w * 8 + rA) * 512 + ka + ksx * 8;
        __builtin_amdgcn_global_load_lds((const GLOBAL_AS unsigned*)s,
            (LOCAL_AS unsigned*)(dA + (j * 8 + w) * 1024), 16, 0, 0);
    }
#pragma unroll
    for (int j = 0; j < 4; ++j) {
        const f16* s = ehlT + (size_t)(cbn + j * 64 + w * 8 + rA) * 512 + kb + ksx * 8;
        __builtin_amdgcn_global_load_lds((const GLOBAL_AS unsigned*)s,
            (LOCAL_AS unsigned*)(dB + (j * 8 + w) * 1024), 16, 0, 0);
    }
}

__global__ __launch_bounds__(512, 2) void k_argmin_mfma(const f16* __restrict__ xhl,
                                                        const f16* __restrict__ ehlT,
                                                        const float* __restrict__ enorm2,
                                                        int* __restrict__ ind,
                                                        float* __restrict__ out_ind) {
    __shared__ char lds[LDS_SZ];
    float* PV = (float*)(lds + LDS_PV);
    int*   PI = (int*)(lds + LDS_PI);
    const int tid  = threadIdx.x;
    const int lane = tid & 63;
    const int w    = tid >> 6;        // wave 0..7
    const int wr   = w >> 2;          // 0/1 : rows wr*128..+128
    const int wc   = w & 3;           // 0..3: cols wc*64..+64 within slab
    const int rb   = blockIdx.x * 256;
    const int l15  = lane & 15;
    const int lkh  = lane >> 4;       // 0..3
    const int rA   = lane >> 3;       // staging: row-in-chunk
    const int ksx  = (lane & 7) ^ (lane >> 3);  // staging: pre-swizzled k-slot

    // init PV/PI
    PV[tid] = FLT_MAX; PV[tid + 512] = FLT_MAX;
    PI[tid] = 0x7fffffff; PI[tid + 512] = 0x7fffffff;

    // preload e2 for all 4 slabs (keep VMEM out of the pipelined loop)
    float e2a[4][4];
#pragma unroll
    for (int s = 0; s < 4; ++s)
#pragma unroll
        for (int fc = 0; fc < 4; ++fc)
            e2a[s][fc] = enorm2[s * 256 + wc * 64 + fc * 16 + l15];

    f32x4 acc[8][4];
#pragma unroll
    for (int i = 0; i < 8; ++i)
#pragma unroll
        for (int j = 0; j < 4; ++j) acc[i][j] = (f32x4){0.f, 0.f, 0.f, 0.f};

    // prologue: stage tile 0 into buf0
    stage_tile(xhl, ehlT, lds + LDS_A0, lds + LDS_B0, rb, 0, w, rA, ksx);

    int p = 0;
    for (int g = 0; g < 48; ++g) {
        // ---- barrier A: all waves done reading buf[p^1] (tile g-1) ----
        asm volatile("" ::: "memory");
        __builtin_amdgcn_s_barrier();
        asm volatile("" ::: "memory");
        // ---- issue next tile's 8 loads into buf[p^1] ----
        if (g < 47) {
            stage_tile(xhl, ehlT,
                       lds + (p ? LDS_A0 : LDS_A1), lds + (p ? LDS_B0 : LDS_B1),
                       rb, g + 1, w, rA, ksx);
            asm volatile("s_waitcnt vmcnt(8)" ::: "memory");  // tile g's 8 (oldest) landed
        } else {
            asm volatile("s_waitcnt vmcnt(0)" ::: "memory");
        }
        // ---- barrier B: all waves' tile-g data visible ----
        __builtin_amdgcn_s_barrier();
        __builtin_amdgcn_sched_barrier(0);

        // ---- 4 phases: (ks,h) = (0,0),(0,1),(1,0),(1,1); no internal barriers ----
        const char* A = lds + (p ? LDS_A1 : LDS_A0);
        const char* B = lds + (p ? LDS_B1 : LDS_B0);
        half8 bf[4];
#pragma unroll
        for (int q = 0; q < 4; ++q) {
            const int ks = q >> 1, h = q & 1;
            if (h == 0) {
#pragma unroll
                for (int fc = 0; fc < 4; ++fc) {
                    int col = wc * 64 + fc * 16 + l15;
                    bf[fc] = *(const half8*)(B + col * 128 +
                                             (((ks * 4 + lkh) * 16) ^ ((col & 7) << 4)));
                }
            }
            half8 af[4];
#pragma unroll
            for (int f = 0; f < 4; ++f) {
                int row = wr * 128 + (h * 4 + f) * 16 + l15;
                af[f] = *(const half8*)(A + row * 128 +
                                        (((ks * 4 + lkh) * 16) ^ ((row & 7) << 4)));
            }
            __builtin_amdgcn_s_setprio(1);
#pragma unroll
            for (int f = 0; f < 4; ++f)
#pragma unroll
                for (int fc = 0; fc < 4; ++fc)
                    acc[h * 4 + f][fc] = __builtin_amdgcn_mfma_f32_16x16x32_f16(
                        af[f], bf[fc], acc[h * 4 + f][fc], 0, 0, 0);
            __builtin_amdgcn_s_setprio(0);
        }

        // ---- slab epilogue: fold acc into PV/PI, reset acc ----
        if ((g % 12) == 11) {
            const int slab = g / 12;
            const int cb = slab * 256;
#pragma unroll
            for (int fr = 0; fr < 8; ++fr)
#pragma unroll
                for (int r = 0; r < 4; ++r) {
                    float best = FLT_MAX; int bidx = 0x7fffffff;
#pragma unroll
                    for (int fc = 0; fc < 4; ++fc) {
                        float sc = fmaf(-2.f, acc[fr][fc][r], e2a[slab][fc]);
                        int col = cb + wc * 64 + fc * 16 + l15;
                        if (sc < best) { best = sc; bidx = col; }  // ascending fc: lowest col wins ties
                    }
#pragma unroll
                    for (int m = 1; m <= 8; m <<= 1) {
                        float ov = __shfl_xor(best, m, 64);
                        int   oi = __shfl_xor(bidx, m, 64);
                        if (ov < best || (ov == best && oi < bidx)) { best = ov; bidx = oi; }
                    }
                    if (l15 == 0) {
                        int row = wr * 128 + fr * 16 + lkh * 4 + r;
                        float pv = PV[row * 4 + wc]; int pi = PI[row * 4 + wc];
                        if (best < pv || (best == pv && bidx < pi)) {
                            PV[row * 4 + wc] = best; PI[row * 4 + wc] = bidx;
                        }
                    }
                }
#pragma unroll
            for (int i = 0; i < 8; ++i)
#pragma unroll
                for (int j = 0; j < 4; ++j) acc[i][j] = (f32x4){0.f, 0.f, 0.f, 0.f};
        }
        p ^= 1;
    }

    __syncthreads();
    if (tid < 256) {
        float best = PV[tid * 4]; int bidx = PI[tid * 4];
#pragma unroll
        for (int t = 1; t < 4; ++t) {
            float v = PV[tid * 4 + t]; int i = PI[tid * 4 + t];
            if (v < best || (v == best && i < bidx)) { best = v; bidx = i; }
        }
        ind[rb + tid] = bidx;
        out_ind[rb + tid] = (float)bidx;
    }
}

// ---------- K2: quantize_st output + per-block diff partials ----------
__global__ __launch_bounds__(256) void k_quant(const float* __restrict__ input,
                                               const float* __restrict__ embedT,
                                               const int* __restrict__ ind,
                                               float* __restrict__ out_q,
                                               float* __restrict__ partials) {
    const int tid = threadIdx.x;
    const unsigned gid = blockIdx.x * 256 + tid;
    float s = 0.f;
#pragma unroll
    for (int j = 0; j < 8; j++) {
        size_t i4 = (size_t)gid + (size_t)j * 524288u;   // 4194304 float4 total
        int row = (int)(i4 >> 6);
        int d4  = (int)(i4 & 63);
        float4 iv = *reinterpret_cast<const float4*>(input + i4 * 4);
        int k = ind[row];
        float4 qv = *reinterpret_cast<const float4*>(embedT + (size_t)k * DIM + d4 * 4);
        float dx = qv.x - iv.x, dy = qv.y - iv.y, dz = qv.z - iv.z, dw = qv.w - iv.w;
        float4 ov;
        ov.x = iv.x + dx; ov.y = iv.y + dy; ov.z = iv.z + dz; ov.w = iv.w + dw;
        *reinterpret_cast<float4*>(out_q + i4 * 4) = ov;
        s += dx * dx + dy * dy + dz * dz + dw * dw;
    }
    __shared__ float red[256];
    red[tid] = s;
    __syncthreads();
    for (int off = 128; off > 0; off >>= 1) {
        if (tid < off) red[tid] += red[tid + off];
        __syncthreads();
    }
    if (tid == 0) partials[blockIdx.x] = red[0];
}

// ---------- K2b: finalize diff ----------
__global__ __launch_bounds__(256) void k_diff(const float* __restrict__ partials,
                                              float* __restrict__ out_diff) {
    __shared__ float red[256];
    int tid = threadIdx.x;
    float s = 0.f;
    for (int j = 0; j < 8; j++) s += partials[tid * 8 + j];
    red[tid] = s;
    __syncthreads();
    for (int off = 128; off > 0; off >>= 1) {
        if (tid < off) red[tid] += red[tid + off];
        __syncthreads();
    }
    if (tid == 0) out_diff[0] = red[0] / 16777216.0f;
}

// ---------- K3: histogram of assignments ----------
__global__ __launch_bounds__(256) void k_hist(const int* __restrict__ ind,
                                              int* __restrict__ counts) {
    __shared__ int h[NEMB];
    int tid = threadIdx.x;
    for (int j = tid; j < NEMB; j += 256) h[j] = 0;
    __syncthreads();
    for (int i = blockIdx.x * 256 + tid; i < NROWS; i += 64 * 256)
        atomicAdd(&h[ind[i]], 1);
    __syncthreads();
    for (int j = tid; j < NEMB; j += 256)
        if (h[j]) atomicAdd(&counts[j], h[j]);
}

// ---------- K4: scans (row offsets + sub-chunk offsets); ncs, n, cs ----------
__global__ __launch_bounds__(1024) void k_scan(const int* __restrict__ counts,
                                               const float* __restrict__ cluster_size,
                                               int* __restrict__ offsets,
                                               int* __restrict__ cursor,
                                               int* __restrict__ substart,
                                               float* __restrict__ out_ncs,
                                               float* __restrict__ cs) {
    __shared__ int sh[NEMB];
    __shared__ float shf[NEMB];
    int tid = threadIdx.x;
    int c = counts[tid];
    sh[tid] = c;
    __syncthreads();
    for (int off = 1; off < NEMB; off <<= 1) {
        int t = (tid >= off) ? sh[tid - off] : 0;
        __syncthreads();
        sh[tid] += t;
        __syncthreads();
    }
    int excl = sh[tid] - c;
    offsets[tid] = excl;
    cursor[tid]  = excl;
    int sc = (c + CH - 1) / CH;
    __syncthreads();
    sh[tid] = sc;
    __syncthreads();
    for (int off = 1; off < NEMB; off <<= 1) {
        int t = (tid >= off) ? sh[tid - off] : 0;
        __syncthreads();
        sh[tid] += t;
        __syncthreads();
    }
    substart[tid] = sh[tid] - sc;
    if (tid == NEMB - 1) substart[NEMB] = sh[tid];
    float ncs = cluster_size[tid] * DECAY + (1.f - DECAY) * (float)c;
    out_ncs[tid] = ncs;
    shf[tid] = ncs;
    __syncthreads();
    for (int off = 512; off > 0; off >>= 1) {
        if (tid < off) shf[tid] += shf[tid + off];
        __syncthreads();
    }
    float n = shf[0];
    cs[tid] = (ncs + EPS) / (n + NEMB * EPS) * n;
}

// ---------- K5: scatter rows by cluster ----------
__global__ __launch_bounds__(256) void k_scatter(const int* __restrict__ ind,
                                                 int* __restrict__ cursor,
                                                 int* __restrict__ sorted) {
    int i = blockIdx.x * 256 + threadIdx.x;
    int k = ind[i];
    int pos = atomicAdd(&cursor[k], 1);
    sorted[pos] = i;
}

// ---------- K6a: balanced partial sums. block = one 64-row sub-chunk ----------
__global__ __launch_bounds__(256) void k_psum(const float* __restrict__ input,
                                              const int* __restrict__ sorted,
                                              const int* __restrict__ counts,
                                              const int* __restrict__ offsets,
                                              const int* __restrict__ substart,
                                              float* __restrict__ partial) {
    const int b = blockIdx.x;
    if (b >= substart[NEMB]) return;
    int lo = 0, hi = NEMB;
    while (hi - lo > 1) {
        int mid = (lo + hi) >> 1;
        if (substart[mid] <= b) lo = mid; else hi = mid;
    }
    const int k     = lo;
    const int chunk = b - substart[k];
    const int cnt   = counts[k];
    const int base  = offsets[k] + chunk * CH;
    const int lim   = min(CH, cnt - chunk * CH);
    const int d     = threadIdx.x;
    float s = 0.f;
    for (int i = 0; i < lim; i++) {
        int row = sorted[base + i];
        s += input[(size_t)row * DIM + d];
    }
    partial[(size_t)b * DIM + d] = s;
}

// ---------- K6b: per-cluster combine (fixed order) + EMA + new_embed ----------
__global__ __launch_bounds__(256) void k_ema(const float* __restrict__ partial,
                                             const float* __restrict__ embed_avg,
                                             const int* __restrict__ substart,
                                             const float* __restrict__ cs,
                                             float* __restrict__ out_navg,
                                             float* __restrict__ out_nembed) {
    const int d = blockIdx.x;
    const int t = threadIdx.x;
#pragma unroll
    for (int i = 0; i < 4; i++) {
        int k = t + 256 * i;
        int s0 = substart[k], s1 = substart[k + 1];
        float s = 0.f;
        for (int sub = s0; sub < s1; sub++)
            s += partial[(size_t)sub * DIM + d];
        float navg = embed_avg[(size_t)d * NEMB + k] * (DECAY * DECAY) + (1.f - DECAY) * s;
        out_navg[(size_t)d * NEMB + k] = navg;
        out_nembed[(size_t)d * NEMB + k] = navg / cs[k];
    }
}

extern "C" void kernel_launch(void* const* d_in, const int* in_sizes, int n_in,
                              void* d_out, int out_size, void* d_ws, size_t ws_size,
                              hipStream_t stream) {
    const float* input        = (const float*)d_in[0];
    const float* embed        = (const float*)d_in[1];
    const float* cluster_size = (const float*)d_in[2];
    const float* embed_avg    = (const float*)d_in[3];

    float* out        = (float*)d_out;
    float* out_q      = out;                       // 16777216
    float* out_diff   = out + 16777216;            // 1
    float* out_ind    = out + 16777217;            // 65536
    float* out_ncs    = out + 16842753;            // 1024
    float* out_navg   = out + 16843777;            // 262144
    float* out_nembed = out + 17105921;            // 262144

    // xhl f16[65536][512] = 64MB: scratch in the out_q region (overwritten by k_quant later)
    f16* xhl = (f16*)out_q;

    char* ws = (char*)d_ws;
    size_t o = 0;
    int*   w_ind      = (int*)(ws + o);   o += (size_t)NROWS * 4;
    float* w_embedT   = (float*)(ws + o); o += (size_t)DIM * NEMB * 4;
    float* w_enorm    = (float*)(ws + o); o += NEMB * 4;
    int*   w_counts   = (int*)(ws + o);   o += NEMB * 4;
    int*   w_offsets  = (int*)(ws + o);   o += NEMB * 4;
    int*   w_cursor   = (int*)(ws + o);   o += NEMB * 4;
    float* w_cs       = (float*)(ws + o); o += NEMB * 4;
    float* w_partials = (float*)(ws + o); o += 2048 * 4;
    int*   w_sorted   = (int*)(ws + o);   o += (size_t)NROWS * 4;
    int*   w_substart = (int*)(ws + o);   o += (NEMB + 4) * 4;
    float* w_partial  = (float*)(ws + o); o += (size_t)MAXSUB * DIM * 4;
    f16*   w_ehlT     = (f16*)(ws + o);   o += (size_t)NEMB * 512 * 2;

    k_enorm<<<16, 256, 0, stream>>>(embed, w_enorm, w_counts);
    k_prep<<<dim3(32, 8), dim3(32, 8), 0, stream>>>(embed, w_embedT, w_ehlT);
    k_xsplit<<<4096, 512, 0, stream>>>(input, xhl);
    k_argmin_mfma<<<256, 512, 0, stream>>>(xhl, w_ehlT, w_enorm, w_ind, out_ind);
    k_quant<<<2048, 256, 0, stream>>>(input, w_embedT, w_ind, out_q, w_partials);
    k_diff<<<1, 256, 0, stream>>>(w_partials, out_diff);
    k_hist<<<64, 256, 0, stream>>>(w_ind, w_counts);
    k_scan<<<1, 1024, 0, stream>>>(w_counts, cluster_size, w_offsets, w_cursor,
                                   w_substart, out_ncs, w_cs);
    k_scatter<<<NROWS / 256, 256, 0, stream>>>(w_ind, w_cursor, w_sorted);
    k_psum<<<MAXSUB, 256, 0, stream>>>(input, w_sorted, w_counts, w_offsets,
                                       w_substart, w_partial);
    k_ema<<<DIM, 256, 0, stream>>>(w_partial, embed_avg, w_substart, w_cs,
                                   out_navg, out_nembed);
}